// Round 1
// baseline (2196.668 us; speedup 1.0000x reference)
//
#include <hip/hip_runtime.h>
#include <hip/hip_bf16.h>

// GConv: out = relu( Agg(support) + x@loop_W + bias ),
//   support = x@W, Agg[b,r,:] += val_e * support[b, c_e, :]
// B=2, N=10000, DIN=DOUT=256, E=320000 (E taken from in_sizes).

#define NN 10000
#define DK 256
#define DO 256

// ---------------- Kernel 1: dual GEMM ----------------
// support[m,:] = X[m,:] @ W ; outv[m,:] = X[m,:] @ LW + bias
// tile 64(M) x 64(N), K-step 32. 256 threads (16x16), 4x4 per thread per matrix.
__global__ __launch_bounds__(256) void gemm_dual(
    const float* __restrict__ X, const float* __restrict__ W,
    const float* __restrict__ LW, const float* __restrict__ bias,
    float* __restrict__ support, float* __restrict__ outv, int Mtotal)
{
    __shared__ float xs[32][65];      // [k][m], padded stride 65
    __shared__ float wsh[2][32][64];  // [which][k][n]

    const int t  = threadIdx.x;
    const int tx = t % 16;
    const int ty = t / 16;
    const int m0 = blockIdx.x * 64;
    const int n0 = blockIdx.y * 64;

    float acc0[4][4] = {};
    float acc1[4][4] = {};

    for (int k0 = 0; k0 < DK; k0 += 32) {
        // ---- load X tile (64 rows x 32 k) transposed into xs[k][m] ----
        {
            const int ml = t / 4;          // 0..63 local row
            const int kq = (t % 4) * 4;    // 0,4,8,12
            const int grow = m0 + ml;
            float4 a = make_float4(0.f, 0.f, 0.f, 0.f);
            float4 b = make_float4(0.f, 0.f, 0.f, 0.f);
            if (grow < Mtotal) {
                a = *(const float4*)&X[(size_t)grow * DK + k0 + kq];
                b = *(const float4*)&X[(size_t)grow * DK + k0 + 16 + kq];
            }
            xs[kq + 0][ml] = a.x; xs[kq + 1][ml] = a.y;
            xs[kq + 2][ml] = a.z; xs[kq + 3][ml] = a.w;
            xs[kq + 16][ml] = b.x; xs[kq + 17][ml] = b.y;
            xs[kq + 18][ml] = b.z; xs[kq + 19][ml] = b.w;
        }
        // ---- load W / LW tiles (32 k x 64 n) ----
        {
            const int kr = t / 8;          // 0..31
            const int cg = (t % 8) * 8;    // 0,8,...,56
            const float* wp = &W[(size_t)(k0 + kr) * DO + n0 + cg];
            const float* lp = &LW[(size_t)(k0 + kr) * DO + n0 + cg];
            *(float4*)&wsh[0][kr][cg]     = *(const float4*)wp;
            *(float4*)&wsh[0][kr][cg + 4] = *(const float4*)(wp + 4);
            *(float4*)&wsh[1][kr][cg]     = *(const float4*)lp;
            *(float4*)&wsh[1][kr][cg + 4] = *(const float4*)(lp + 4);
        }
        __syncthreads();

        #pragma unroll
        for (int kk = 0; kk < 32; ++kk) {
            float xv[4], wv[4], lv[4];
            #pragma unroll
            for (int i = 0; i < 4; ++i) xv[i] = xs[kk][ty * 4 + i];
            const float4 w4 = *(const float4*)&wsh[0][kk][tx * 4];
            const float4 l4 = *(const float4*)&wsh[1][kk][tx * 4];
            wv[0] = w4.x; wv[1] = w4.y; wv[2] = w4.z; wv[3] = w4.w;
            lv[0] = l4.x; lv[1] = l4.y; lv[2] = l4.z; lv[3] = l4.w;
            #pragma unroll
            for (int i = 0; i < 4; ++i)
                #pragma unroll
                for (int j = 0; j < 4; ++j) {
                    acc0[i][j] += xv[i] * wv[j];
                    acc1[i][j] += xv[i] * lv[j];
                }
        }
        __syncthreads();
    }

    // ---- epilogue ----
    const int col = n0 + tx * 4;
    const float4 b4 = *(const float4*)&bias[col];
    #pragma unroll
    for (int i = 0; i < 4; ++i) {
        const int grow = m0 + ty * 4 + i;
        if (grow >= Mtotal) break;
        float4 s, o;
        s.x = acc0[i][0]; s.y = acc0[i][1]; s.z = acc0[i][2]; s.w = acc0[i][3];
        o.x = acc1[i][0] + b4.x; o.y = acc1[i][1] + b4.y;
        o.z = acc1[i][2] + b4.z; o.w = acc1[i][3] + b4.w;
        *(float4*)&support[(size_t)grow * DO + col] = s;
        *(float4*)&outv[(size_t)grow * DO + col]    = o;
    }
}

// ---------------- Kernel 2: edge scatter (atomic) ----------------
// 64 lanes per edge; each lane handles 4 consecutive features for both batches.
__global__ __launch_bounds__(256) void edge_scatter(
    const float* __restrict__ support, const float* __restrict__ vals,
    const int* __restrict__ rows, const int* __restrict__ cols,
    float* __restrict__ outv, int E)
{
    const long long idx = (long long)blockIdx.x * 256 + threadIdx.x;
    const int e = (int)(idx >> 6);
    if (e >= E) return;
    const int d = (int)(idx & 63) * 4;
    const float v = vals[e];
    const int r = rows[e];
    const int c = cols[e];
    #pragma unroll
    for (int b = 0; b < 2; ++b) {
        const float4 s = *(const float4*)&support[((size_t)b * NN + c) * DO + d];
        float* o = &outv[((size_t)b * NN + r) * DO + d];
        atomicAdd(o + 0, v * s.x);
        atomicAdd(o + 1, v * s.y);
        atomicAdd(o + 2, v * s.z);
        atomicAdd(o + 3, v * s.w);
    }
}

// ---------------- Kernel 3: ReLU ----------------
__global__ __launch_bounds__(256) void relu_k(float* __restrict__ o, int n4)
{
    const int i = blockIdx.x * 256 + threadIdx.x;
    if (i >= n4) return;
    float4 v = *(float4*)&((float4*)o)[i];
    v.x = fmaxf(v.x, 0.f); v.y = fmaxf(v.y, 0.f);
    v.z = fmaxf(v.z, 0.f); v.w = fmaxf(v.w, 0.f);
    ((float4*)o)[i] = v;
}

extern "C" void kernel_launch(void* const* d_in, const int* in_sizes, int n_in,
                              void* d_out, int out_size, void* d_ws, size_t ws_size,
                              hipStream_t stream)
{
    const float* x    = (const float*)d_in[0];
    const float* W    = (const float*)d_in[1];
    const float* LW   = (const float*)d_in[2];
    const float* bias = (const float*)d_in[3];
    const float* ev   = (const float*)d_in[4];
    const int*   rows = (const int*)d_in[5];
    const int*   cols = (const int*)d_in[6];
    float* out = (float*)d_out;
    float* support = (float*)d_ws;   // B*N*DO floats = 20.48 MB

    const int E = in_sizes[4];
    const int Mtotal = in_sizes[0] / DK;   // B*N = 20000

    dim3 g1((Mtotal + 63) / 64, DO / 64);
    gemm_dual<<<g1, 256, 0, stream>>>(x, W, LW, bias, support, out, Mtotal);

    const long long scatterThreads = (long long)E * 64;
    const int scatterBlocks = (int)((scatterThreads + 255) / 256);
    edge_scatter<<<scatterBlocks, 256, 0, stream>>>(support, ev, rows, cols, out, E);

    const int n4 = out_size / 4;
    relu_k<<<(n4 + 255) / 256, 256, 0, stream>>>(out, n4);
}

// Round 2
// 223.755 us; speedup vs baseline: 9.8173x; 9.8173x over previous
//
#include <hip/hip_runtime.h>
#include <hip/hip_bf16.h>

// GConv: out = relu( Agg(support) + x@loop_W + bias ),
//   support = x@W, Agg[b,r,:] += val_e * support[b, c_e, :]
// B=2, N=10000, DIN=DOUT=256. E from in_sizes.
// R1: replace 163.8M global atomics with on-device CSR build + per-row
//     gather-aggregate (atomic-free inner loop), fuse ReLU epilogue.

#define NN 10000
#define DK 256
#define DO 256
#define SCAN_T 256
#define SCAN_C 40   // SCAN_T*SCAN_C = 10240 >= NN

// ---------------- Kernel 1: dual GEMM ----------------
__global__ __launch_bounds__(256) void gemm_dual(
    const float* __restrict__ X, const float* __restrict__ W,
    const float* __restrict__ LW, const float* __restrict__ bias,
    float* __restrict__ support, float* __restrict__ outv, int Mtotal)
{
    __shared__ float xs[32][65];      // [k][m], padded
    __shared__ float wsh[2][32][64];  // [which][k][n]

    const int t  = threadIdx.x;
    const int tx = t % 16;
    const int ty = t / 16;
    const int m0 = blockIdx.x * 64;
    const int n0 = blockIdx.y * 64;

    float acc0[4][4] = {};
    float acc1[4][4] = {};

    for (int k0 = 0; k0 < DK; k0 += 32) {
        {
            const int ml = t / 4;
            const int kq = (t % 4) * 4;
            const int grow = m0 + ml;
            float4 a = make_float4(0.f, 0.f, 0.f, 0.f);
            float4 b = make_float4(0.f, 0.f, 0.f, 0.f);
            if (grow < Mtotal) {
                a = *(const float4*)&X[(size_t)grow * DK + k0 + kq];
                b = *(const float4*)&X[(size_t)grow * DK + k0 + 16 + kq];
            }
            xs[kq + 0][ml] = a.x; xs[kq + 1][ml] = a.y;
            xs[kq + 2][ml] = a.z; xs[kq + 3][ml] = a.w;
            xs[kq + 16][ml] = b.x; xs[kq + 17][ml] = b.y;
            xs[kq + 18][ml] = b.z; xs[kq + 19][ml] = b.w;
        }
        {
            const int kr = t / 8;
            const int cg = (t % 8) * 8;
            const float* wp = &W[(size_t)(k0 + kr) * DO + n0 + cg];
            const float* lp = &LW[(size_t)(k0 + kr) * DO + n0 + cg];
            *(float4*)&wsh[0][kr][cg]     = *(const float4*)wp;
            *(float4*)&wsh[0][kr][cg + 4] = *(const float4*)(wp + 4);
            *(float4*)&wsh[1][kr][cg]     = *(const float4*)lp;
            *(float4*)&wsh[1][kr][cg + 4] = *(const float4*)(lp + 4);
        }
        __syncthreads();

        #pragma unroll
        for (int kk = 0; kk < 32; ++kk) {
            float xv[4];
            #pragma unroll
            for (int i = 0; i < 4; ++i) xv[i] = xs[kk][ty * 4 + i];
            const float4 w4 = *(const float4*)&wsh[0][kk][tx * 4];
            const float4 l4 = *(const float4*)&wsh[1][kk][tx * 4];
            const float wv[4] = {w4.x, w4.y, w4.z, w4.w};
            const float lv[4] = {l4.x, l4.y, l4.z, l4.w};
            #pragma unroll
            for (int i = 0; i < 4; ++i)
                #pragma unroll
                for (int j = 0; j < 4; ++j) {
                    acc0[i][j] += xv[i] * wv[j];
                    acc1[i][j] += xv[i] * lv[j];
                }
        }
        __syncthreads();
    }

    const int col = n0 + tx * 4;
    const float4 b4 = *(const float4*)&bias[col];
    #pragma unroll
    for (int i = 0; i < 4; ++i) {
        const int grow = m0 + ty * 4 + i;
        if (grow >= Mtotal) break;
        float4 s, o;
        s.x = acc0[i][0]; s.y = acc0[i][1]; s.z = acc0[i][2]; s.w = acc0[i][3];
        o.x = acc1[i][0] + b4.x; o.y = acc1[i][1] + b4.y;
        o.z = acc1[i][2] + b4.z; o.w = acc1[i][3] + b4.w;
        *(float4*)&support[(size_t)grow * DO + col] = s;
        *(float4*)&outv[(size_t)grow * DO + col]    = o;
    }
}

// ---------------- CSR build ----------------
__global__ __launch_bounds__(256) void zero_counts(int* __restrict__ counts, int n)
{
    const int i = blockIdx.x * 256 + threadIdx.x;
    if (i < n) counts[i] = 0;
}

__global__ __launch_bounds__(256) void hist_rows(
    const int* __restrict__ rows, int* __restrict__ counts, int E)
{
    const int e = blockIdx.x * 256 + threadIdx.x;
    if (e < E) atomicAdd(&counts[rows[e]], 1);
}

// one block: exclusive scan of counts[0..NN) -> offsets, cursor
__global__ __launch_bounds__(SCAN_T) void scan_rows(
    const int* __restrict__ counts, int* __restrict__ offsets,
    int* __restrict__ cursor)
{
    __shared__ int sums[SCAN_T];
    const int t = threadIdx.x;
    int local[SCAN_C];
    int s = 0;
    const int base = t * SCAN_C;
    #pragma unroll
    for (int i = 0; i < SCAN_C; ++i) {
        const int idx = base + i;
        const int c = (idx < NN) ? counts[idx] : 0;
        local[i] = s;
        s += c;
    }
    sums[t] = s;
    __syncthreads();
    // Hillis-Steele inclusive scan
    for (int off = 1; off < SCAN_T; off <<= 1) {
        int u = (t >= off) ? sums[t - off] : 0;
        __syncthreads();
        sums[t] += u;
        __syncthreads();
    }
    const int excl = (t == 0) ? 0 : sums[t - 1];
    #pragma unroll
    for (int i = 0; i < SCAN_C; ++i) {
        const int idx = base + i;
        if (idx < NN) {
            const int o = excl + local[i];
            offsets[idx] = o;
            cursor[idx]  = o;
        }
    }
}

__global__ __launch_bounds__(256) void scatter_edges(
    const int* __restrict__ rows, const int* __restrict__ cols,
    const float* __restrict__ vals, int* __restrict__ cursor,
    float2* __restrict__ epack, int E)
{
    const int e = blockIdx.x * 256 + threadIdx.x;
    if (e >= E) return;
    const int p = atomicAdd(&cursor[rows[e]], 1);
    epack[p] = make_float2(__int_as_float(cols[e]), vals[e]);
}

// ---------------- Kernel: per-row aggregate + ReLU ----------------
// one wave per row; lane handles 4 feats for both batches.
__global__ __launch_bounds__(256) void agg_relu(
    const float* __restrict__ support, const float2* __restrict__ epack,
    const int* __restrict__ offsets, const int* __restrict__ counts,
    float* __restrict__ outv)
{
    const int widx = (blockIdx.x * 256 + threadIdx.x) >> 6;
    if (widx >= NN) return;
    const int lane = threadIdx.x & 63;
    const int d = lane * 4;
    const int r = widx;
    const int start = offsets[r];
    const int deg   = counts[r];

    float4 acc0 = make_float4(0.f, 0.f, 0.f, 0.f);
    float4 acc1 = make_float4(0.f, 0.f, 0.f, 0.f);

    #pragma unroll 2
    for (int i = 0; i < deg; ++i) {
        const float2 ep = epack[start + i];
        const int col = __float_as_int(ep.x);
        const float v = ep.y;
        const float4 s0 = *(const float4*)&support[(size_t)col * DO + d];
        const float4 s1 = *(const float4*)&support[((size_t)NN + col) * DO + d];
        acc0.x += v * s0.x; acc0.y += v * s0.y;
        acc0.z += v * s0.z; acc0.w += v * s0.w;
        acc1.x += v * s1.x; acc1.y += v * s1.y;
        acc1.z += v * s1.z; acc1.w += v * s1.w;
    }

    float* o0 = &outv[(size_t)r * DO + d];
    float* o1 = &outv[((size_t)NN + r) * DO + d];
    float4 a = *(const float4*)o0;
    float4 b = *(const float4*)o1;
    a.x = fmaxf(a.x + acc0.x, 0.f); a.y = fmaxf(a.y + acc0.y, 0.f);
    a.z = fmaxf(a.z + acc0.z, 0.f); a.w = fmaxf(a.w + acc0.w, 0.f);
    b.x = fmaxf(b.x + acc1.x, 0.f); b.y = fmaxf(b.y + acc1.y, 0.f);
    b.z = fmaxf(b.z + acc1.z, 0.f); b.w = fmaxf(b.w + acc1.w, 0.f);
    *(float4*)o0 = a;
    *(float4*)o1 = b;
}

extern "C" void kernel_launch(void* const* d_in, const int* in_sizes, int n_in,
                              void* d_out, int out_size, void* d_ws, size_t ws_size,
                              hipStream_t stream)
{
    const float* x    = (const float*)d_in[0];
    const float* W    = (const float*)d_in[1];
    const float* LW   = (const float*)d_in[2];
    const float* bias = (const float*)d_in[3];
    const float* ev   = (const float*)d_in[4];
    const int*   rows = (const int*)d_in[5];
    const int*   cols = (const int*)d_in[6];
    float* out = (float*)d_out;

    const int E = in_sizes[4];
    const int Mtotal = in_sizes[0] / DK;   // B*N = 20000

    // workspace layout
    char* wsb = (char*)d_ws;
    float* support = (float*)wsb;                               // 20,480,000 B
    int*   counts  = (int*)(wsb + 20480000);                    // 40,000 B
    int*   offsets = (int*)(wsb + 20520000);                    // 40,000 B
    int*   cursor  = (int*)(wsb + 20560000);                    // 40,000 B
    float2* epack  = (float2*)(wsb + 20600000);                 // 8*E B

    dim3 g1((Mtotal + 63) / 64, DO / 64);
    gemm_dual<<<g1, 256, 0, stream>>>(x, W, LW, bias, support, out, Mtotal);

    zero_counts<<<(NN + 255) / 256, 256, 0, stream>>>(counts, NN);
    hist_rows<<<(E + 255) / 256, 256, 0, stream>>>(rows, counts, E);
    scan_rows<<<1, SCAN_T, 0, stream>>>(counts, offsets, cursor);
    scatter_edges<<<(E + 255) / 256, 256, 0, stream>>>(rows, cols, ev, cursor, epack, E);

    const int aggBlocks = (NN * 64 + 255) / 256;
    agg_relu<<<aggBlocks, 256, 0, stream>>>(support, epack, offsets, counts, out);
}

// Round 3
// 134.011 us; speedup vs baseline: 16.3917x; 1.6697x over previous
//
#include <hip/hip_runtime.h>
#include <hip/hip_bf16.h>

// GConv: out = relu( Agg(support) + x@loop_W + bias )
// R2: bf16 MFMA dual GEMM (16x16x32, XOR-swizzled LDS subtiles),
//     bf16 support for agg gather, (row,batch)-wave agg split.

#define NN 10000
#define DK 256
#define DO 256
#define MT 20000      // B*N rows
#define SCAN_T 256
#define SCAN_C 40     // 10240 >= NN

typedef short short8 __attribute__((ext_vector_type(8)));
typedef float f32x4 __attribute__((ext_vector_type(4)));

__device__ inline unsigned short f2bf(float f) {
    unsigned int u = __float_as_uint(f);
    u = (u + 0x7FFFu + ((u >> 16) & 1u)) >> 16;   // round-nearest-even
    return (unsigned short)u;
}
__device__ inline float bf2f(unsigned short s) {
    return __uint_as_float(((unsigned int)s) << 16);
}

// ---------------- convert X (f32) -> Xb (bf16) ----------------
__global__ __launch_bounds__(256) void cvt_x(
    const float* __restrict__ X, unsigned short* __restrict__ Xb, int n8)
{
    const int i = blockIdx.x * 256 + threadIdx.x;
    if (i >= n8) return;
    const float4 a = ((const float4*)X)[2 * i];
    const float4 b = ((const float4*)X)[2 * i + 1];
    short8 o;
    o[0] = (short)f2bf(a.x); o[1] = (short)f2bf(a.y);
    o[2] = (short)f2bf(a.z); o[3] = (short)f2bf(a.w);
    o[4] = (short)f2bf(b.x); o[5] = (short)f2bf(b.y);
    o[6] = (short)f2bf(b.z); o[7] = (short)f2bf(b.w);
    *(short8*)&Xb[(size_t)i * 8] = o;
}

// ---------------- transpose+convert W,LW -> Wt,LWt (bf16 [col][k]) ----------------
__global__ __launch_bounds__(256) void transpose_w(
    const float* __restrict__ W, const float* __restrict__ LW,
    unsigned short* __restrict__ Wt, unsigned short* __restrict__ LWt)
{
    __shared__ float tile[64][65];
    const float* src = blockIdx.z ? LW : W;
    unsigned short* dst = blockIdx.z ? LWt : Wt;
    const int k0 = blockIdx.x * 64, c0 = blockIdx.y * 64;
    #pragma unroll
    for (int it = 0; it < 16; ++it) {
        const int u = it * 256 + threadIdx.x;
        const int i = u >> 6, j = u & 63;
        tile[i][j] = src[(size_t)(k0 + i) * DO + c0 + j];
    }
    __syncthreads();
    #pragma unroll
    for (int it = 0; it < 16; ++it) {
        const int u = it * 256 + threadIdx.x;
        const int j = u >> 6, i = u & 63;
        dst[(size_t)(c0 + j) * DK + k0 + i] = f2bf(tile[i][j]);
    }
}

// ---------------- MFMA dual GEMM ----------------
// z=0: support_bf = bf16(Xb @ W);  z=1: out = Xb @ LW + bias (f32)
// block 256 = 4 waves (2x2), block tile 128x128, wave tile 64x64, BK=64.
__global__ __launch_bounds__(256) void gemm_mfma(
    const unsigned short* __restrict__ Xb, const unsigned short* __restrict__ Wt,
    const unsigned short* __restrict__ LWt, const float* __restrict__ bias,
    unsigned short* __restrict__ sup, float* __restrict__ outv)
{
    __shared__ unsigned short As[8][128][8];
    __shared__ unsigned short Bs[8][128][8];
    const int t = threadIdx.x;
    const int wid = t >> 6, lane = t & 63;
    const int wm = wid >> 1, wn = wid & 1;
    const int m0 = blockIdx.x * 128;
    const int n0 = blockIdx.y * 128;
    const bool isLoop = (blockIdx.z != 0);
    const unsigned short* Bsrc = isLoop ? LWt : Wt;

    f32x4 acc[4][4];
    #pragma unroll
    for (int i = 0; i < 4; ++i)
        #pragma unroll
        for (int j = 0; j < 4; ++j)
            acc[i][j] = (f32x4){0.f, 0.f, 0.f, 0.f};

    for (int k0 = 0; k0 < DK; k0 += 64) {
        #pragma unroll
        for (int it = 0; it < 4; ++it) {          // stage A subtiles
            const int u = it * 256 + t;
            const int row = u >> 3, kg = u & 7;
            const int grow = m0 + row;
            short8 v = (short8){0,0,0,0,0,0,0,0};
            if (grow < MT) v = *(const short8*)&Xb[(size_t)grow * DK + k0 + kg * 8];
            *(short8*)&As[kg][row ^ kg][0] = v;
        }
        #pragma unroll
        for (int it = 0; it < 4; ++it) {          // stage B subtiles
            const int u = it * 256 + t;
            const int col = u >> 3, kg = u & 7;
            const short8 v = *(const short8*)&Bsrc[(size_t)(n0 + col) * DK + k0 + kg * 8];
            *(short8*)&Bs[kg][col ^ kg][0] = v;
        }
        __syncthreads();
        #pragma unroll
        for (int s = 0; s < 2; ++s) {             // two k=32 substeps
            const int kg = s * 4 + (lane >> 4);
            short8 af[4], bfv[4];
            #pragma unroll
            for (int i = 0; i < 4; ++i) {
                const int row = wm * 64 + i * 16 + (lane & 15);
                af[i] = *(const short8*)&As[kg][row ^ kg][0];
            }
            #pragma unroll
            for (int j = 0; j < 4; ++j) {
                const int col = wn * 64 + j * 16 + (lane & 15);
                bfv[j] = *(const short8*)&Bs[kg][col ^ kg][0];
            }
            #pragma unroll
            for (int i = 0; i < 4; ++i)
                #pragma unroll
                for (int j = 0; j < 4; ++j)
                    acc[i][j] = __builtin_amdgcn_mfma_f32_16x16x32_bf16(
                        af[i], bfv[j], acc[i][j], 0, 0, 0);
        }
        __syncthreads();
    }

    const int rbase = m0 + wm * 64;
    const int cbase = n0 + wn * 64;
    if (!isLoop) {
        #pragma unroll
        for (int i = 0; i < 4; ++i)
            #pragma unroll
            for (int q = 0; q < 4; ++q) {
                const int row = rbase + i * 16 + (lane >> 4) * 4 + q;
                if (row < MT) {
                    #pragma unroll
                    for (int j = 0; j < 4; ++j) {
                        const int col = cbase + j * 16 + (lane & 15);
                        sup[(size_t)row * DO + col] = f2bf(acc[i][j][q]);
                    }
                }
            }
    } else {
        #pragma unroll
        for (int i = 0; i < 4; ++i)
            #pragma unroll
            for (int q = 0; q < 4; ++q) {
                const int row = rbase + i * 16 + (lane >> 4) * 4 + q;
                if (row < MT) {
                    #pragma unroll
                    for (int j = 0; j < 4; ++j) {
                        const int col = cbase + j * 16 + (lane & 15);
                        outv[(size_t)row * DO + col] = acc[i][j][q] + bias[col];
                    }
                }
            }
    }
}

// ---------------- CSR build ----------------
__global__ __launch_bounds__(256) void zero_counts(int* __restrict__ counts, int n)
{
    const int i = blockIdx.x * 256 + threadIdx.x;
    if (i < n) counts[i] = 0;
}

__global__ __launch_bounds__(256) void hist_rows(
    const int* __restrict__ rows, int* __restrict__ counts, int E)
{
    const int e = blockIdx.x * 256 + threadIdx.x;
    if (e < E) atomicAdd(&counts[rows[e]], 1);
}

__global__ __launch_bounds__(SCAN_T) void scan_rows(
    const int* __restrict__ counts, int* __restrict__ offsets,
    int* __restrict__ cursor)
{
    __shared__ int sums[SCAN_T];
    const int t = threadIdx.x;
    int local[SCAN_C];
    int s = 0;
    const int base = t * SCAN_C;
    #pragma unroll
    for (int i = 0; i < SCAN_C; ++i) {
        const int idx = base + i;
        const int c = (idx < NN) ? counts[idx] : 0;
        local[i] = s;
        s += c;
    }
    sums[t] = s;
    __syncthreads();
    for (int off = 1; off < SCAN_T; off <<= 1) {
        int u = (t >= off) ? sums[t - off] : 0;
        __syncthreads();
        sums[t] += u;
        __syncthreads();
    }
    const int excl = (t == 0) ? 0 : sums[t - 1];
    #pragma unroll
    for (int i = 0; i < SCAN_C; ++i) {
        const int idx = base + i;
        if (idx < NN) {
            const int o = excl + local[i];
            offsets[idx] = o;
            cursor[idx]  = o;
        }
    }
}

__global__ __launch_bounds__(256) void scatter_edges(
    const int* __restrict__ rows, const int* __restrict__ cols,
    const float* __restrict__ vals, int* __restrict__ cursor,
    float2* __restrict__ epack, int E)
{
    const int e = blockIdx.x * 256 + threadIdx.x;
    if (e >= E) return;
    const int p = atomicAdd(&cursor[rows[e]], 1);
    epack[p] = make_float2(__int_as_float(cols[e]), vals[e]);
}

// ---------------- aggregate + ReLU: one wave per (row, batch) ----------------
__global__ __launch_bounds__(256) void agg_relu(
    const unsigned short* __restrict__ sup, const float2* __restrict__ epack,
    const int* __restrict__ offsets, const int* __restrict__ counts,
    float* __restrict__ outv)
{
    const int widx = (blockIdx.x * 256 + threadIdx.x) >> 6;
    if (widx >= 2 * NN) return;
    const int lane = threadIdx.x & 63;
    const int b = widx & 1, r = widx >> 1;
    const int d = lane * 4;
    const size_t supb = (size_t)b * NN * DO + d;
    const int start = offsets[r];
    const int deg   = counts[r];

    float a0 = 0.f, a1 = 0.f, a2 = 0.f, a3 = 0.f;
    #pragma unroll 4
    for (int i = 0; i < deg; ++i) {
        const float2 ep = epack[start + i];
        const int col = __float_as_int(ep.x);
        const float v = ep.y;
        const ushort4 s = *(const ushort4*)&sup[supb + (size_t)col * DO];
        a0 += v * bf2f(s.x); a1 += v * bf2f(s.y);
        a2 += v * bf2f(s.z); a3 += v * bf2f(s.w);
    }

    float* o = &outv[((size_t)b * NN + r) * DO + d];
    float4 t4 = *(const float4*)o;
    t4.x = fmaxf(t4.x + a0, 0.f); t4.y = fmaxf(t4.y + a1, 0.f);
    t4.z = fmaxf(t4.z + a2, 0.f); t4.w = fmaxf(t4.w + a3, 0.f);
    *(float4*)o = t4;
}

extern "C" void kernel_launch(void* const* d_in, const int* in_sizes, int n_in,
                              void* d_out, int out_size, void* d_ws, size_t ws_size,
                              hipStream_t stream)
{
    const float* x    = (const float*)d_in[0];
    const float* W    = (const float*)d_in[1];
    const float* LW   = (const float*)d_in[2];
    const float* bias = (const float*)d_in[3];
    const float* ev   = (const float*)d_in[4];
    const int*   rows = (const int*)d_in[5];
    const int*   cols = (const int*)d_in[6];
    float* out = (float*)d_out;

    const int E = in_sizes[4];

    // workspace layout (epack aliases Xb: scatter runs AFTER gemm reads Xb)
    char* wsb = (char*)d_ws;
    unsigned short* Xb    = (unsigned short*)wsb;              // 10,240,000 B
    float2*         epack = (float2*)wsb;                      // 8*E <= 2.56 MB (alias)
    unsigned short* Wt    = (unsigned short*)(wsb + 10240000); // 131,072 B
    unsigned short* LWt   = (unsigned short*)(wsb + 10371072); // 131,072 B
    unsigned short* supb  = (unsigned short*)(wsb + 10502144); // 10,240,000 B
    int* counts  = (int*)(wsb + 20742144);                     // 40,000 B
    int* offsets = (int*)(wsb + 20782144);                     // 40,000 B
    int* cursor  = (int*)(wsb + 20822144);                     // 40,000 B

    cvt_x<<<(MT * DK / 8 + 255) / 256, 256, 0, stream>>>(x, Xb, MT * DK / 8);
    transpose_w<<<dim3(4, 4, 2), 256, 0, stream>>>(W, LW, Wt, LWt);

    zero_counts<<<(NN + 255) / 256, 256, 0, stream>>>(counts, NN);
    hist_rows<<<(E + 255) / 256, 256, 0, stream>>>(rows, counts, E);
    scan_rows<<<1, SCAN_T, 0, stream>>>(counts, offsets, cursor);

    gemm_mfma<<<dim3((MT + 127) / 128, DO / 128, 2), 256, 0, stream>>>(
        Xb, Wt, LWt, bias, supb, out);

    scatter_edges<<<(E + 255) / 256, 256, 0, stream>>>(rows, cols, ev, cursor, epack, E);

    const int aggBlocks = (2 * NN * 64 + 255) / 256;
    agg_relu<<<aggBlocks, 256, 0, stream>>>(supb, epack, offsets, counts, out);
}